// Round 8
// baseline (129.970 us; speedup 1.0000x reference)
//
#include <hip/hip_runtime.h>

#define NROWS  32768
#define DIM    64
#define KCODES 1024
#define NELEM  (NROWS * DIM)   // 2097152
#define CHUNKS 32
#define CPC    (KCODES / CHUNKS)   // 32 codes per chunk-block
#define GROUPS 64                  // row-groups of 512 rows

typedef float v2f __attribute__((ext_vector_type(2)));

// numpy-style pairwise sum of squares for n=64 contiguous fp32 (contraction
// OFF so squared temps are not fused into adds; matches jnp.sum(w*w)).
// Verified absmax 0.0 in all prior rounds. Used for se (cold path).
__device__ __forceinline__ float np_sumsq64(const float v[64]) {
#pragma clang fp contract(off)
  float r0 = v[0] * v[0];
  float r1 = v[1] * v[1];
  float r2 = v[2] * v[2];
  float r3 = v[3] * v[3];
  float r4 = v[4] * v[4];
  float r5 = v[5] * v[5];
  float r6 = v[6] * v[6];
  float r7 = v[7] * v[7];
#pragma unroll
  for (int i = 8; i < 64; i += 8) {
    r0 += v[i + 0] * v[i + 0];
    r1 += v[i + 1] * v[i + 1];
    r2 += v[i + 2] * v[i + 2];
    r3 += v[i + 3] * v[i + 3];
    r4 += v[i + 4] * v[i + 4];
    r5 += v[i + 5] * v[i + 5];
    r6 += v[i + 6] * v[i + 6];
    r7 += v[i + 7] * v[i + 7];
  }
  return ((r0 + r1) + (r2 + r3)) + ((r4 + r5) + (r6 + r7));
}

// Init (grid 128x256): keys to +inf, per-code ||e||^2 (first 1024 threads).
__global__ __launch_bounds__(256) void vq_prep(const float* __restrict__ w,
                                               float* __restrict__ se,
                                               unsigned long long* __restrict__ keys) {
  const int t = blockIdx.x * 256 + threadIdx.x;  // 0..32767
  keys[t] = ~0ull;

  if (t < KCODES) {
    float v[64];
    const float4* wr = (const float4*)(w + (size_t)t * DIM);
#pragma unroll
    for (int i = 0; i < 16; ++i) {
      float4 q = wr[i];
      v[4 * i + 0] = q.x; v[4 * i + 1] = q.y;
      v[4 * i + 2] = q.z; v[4 * i + 3] = q.w;
    }
    se[t] = np_sumsq64(v);
  }
}

// Phase 2: distances + argmin. M=2 rows/thread, PURE scalar w-feed,
// full 512-VGPR budget.
// Round-7 recalibration (fits all 8 sessions' counters): v_pk_fma_f32 is
// 4 cyc/wave64 (NOT double-rate) -> VALU issue floor ~35us, and every round
// measured busy 35-41us = AT the floor; there was never instruction bloat.
// The 45% stall in the best configs is w-feed latency/BW. Three facts drive
// this design: (a) SMEM+DS share lgkmcnt and SMEM returns out-of-order, so
// mixing pipes forces lgkmcnt(0) convoys (R7 hybrid regression) -> ONE feed
// class; (b) scalar-only is the best measured feed (R1 62.6 vs LDS 85 vs
// hybrid 70); (c) M=2 halves feed-per-FLOP but R4/R5 spilled the 2nd row to
// scratch (WRITE_SIZE 8-10.6MB vs 2MB baseline) because launch_bounds>=2
// caps the allocator at 128 regs. Fix: __launch_bounds__(256,1) -> 512-reg
// budget, ~160-200 used, 3 waves/SIMD — each wave's ~300-cyc compute block
// covers the other waves' K$ latency.
// KILL SIGNALS: VGPR_Count <=128 or WRITE_SIZE >=6MB (spill persists).
//
// Swizzle: xcd=bid&7, m=bid>>3; group=(xcd<<3)|(m>>5), chunk=m&31.
// Same-CU blocks (m = c, c+32, ... under round-robin) share chunk (m&31
// const) -> the 8KB w-chunk is K$-resident after one pass; each XCD hosts
// 8 whole groups (x L2-local); bijective by construction.
//
// fp per row is op-for-op the verified R1/R4 sequence: a0..a3 v2f chains
// over i=0,2,..,14 ascending, ((a0+a1)+(a2+a3)), dot=s.x+s.y,
// d=fma(-2,dot,fl(sx+se[c])); sx = R5/R6's verified v2f np-tree; strict <
// over ascending c; u64 (dist_bits<<32)|c atomicMin merges chunks
// (lowest-index tie-break). Interleaving row b does not alter row a's fp.
__global__ __launch_bounds__(256, 1)
void vq_dist(const float* __restrict__ x,
             const float* __restrict__ w,
             const float* __restrict__ se,
             unsigned long long* __restrict__ keys) {
  const int bid = blockIdx.x;
  const int xcd = bid & 7;
  const int m = bid >> 3;                      // 0..255 within XCD
  const int group = (xcd << 3) | (m >> 5);     // 0..63
  const int chunk = m & 31;                    // same-CU blocks share chunk
  const int t = threadIdx.x;
  const int r0 = group * 512 + t;
  const int r1 = r0 + 256;
  const int c0 = chunk * CPC;
  const float4* w4 = (const float4*)w;

  // Two rows resident (R4-verified prologue): xa/xb[2i],[2i+1] = float4 i.
  v2f xa[32], xb[32];
  {
    const float4* xr0 = (const float4*)(x + (size_t)r0 * DIM);
    const float4* xr1 = (const float4*)(x + (size_t)r1 * DIM);
#pragma unroll
    for (int i = 0; i < 16; ++i) {
      float4 qa = xr0[i];
      xa[2 * i + 0] = (v2f){qa.x, qa.y};
      xa[2 * i + 1] = (v2f){qa.z, qa.w};
      float4 qb = xr1[i];
      xb[2 * i + 0] = (v2f){qb.x, qb.y};
      xb[2 * i + 1] = (v2f){qb.z, qb.w};
    }
  }

  // sx via the verified np tree in v2f form (R5/R6, absmax 0.0).
  float sxa, sxb;
  {
#pragma clang fp contract(off)
    v2f A0 = xa[0] * xa[0], A1 = xa[1] * xa[1];
    v2f A2 = xa[2] * xa[2], A3 = xa[3] * xa[3];
    v2f B0 = xb[0] * xb[0], B1 = xb[1] * xb[1];
    v2f B2 = xb[2] * xb[2], B3 = xb[3] * xb[3];
#pragma unroll
    for (int mm = 1; mm < 8; ++mm) {
      A0 += xa[4 * mm + 0] * xa[4 * mm + 0];
      A1 += xa[4 * mm + 1] * xa[4 * mm + 1];
      A2 += xa[4 * mm + 2] * xa[4 * mm + 2];
      A3 += xa[4 * mm + 3] * xa[4 * mm + 3];
      B0 += xb[4 * mm + 0] * xb[4 * mm + 0];
      B1 += xb[4 * mm + 1] * xb[4 * mm + 1];
      B2 += xb[4 * mm + 2] * xb[4 * mm + 2];
      B3 += xb[4 * mm + 3] * xb[4 * mm + 3];
    }
    sxa = ((A0.x + A0.y) + (A1.x + A1.y)) + ((A2.x + A2.y) + (A3.x + A3.y));
    sxb = ((B0.x + B0.y) + (B1.x + B1.y)) + ((B2.x + B2.y) + (B3.x + B3.y));
  }

  float bda = __builtin_inff(); int bca = 0;
  float bdb = __builtin_inff(); int bcb = 0;

#pragma unroll 2
  for (int j = 0; j < CPC; ++j) {
    const int c = c0 + j;                      // wave-uniform -> s_load path
    const float4* wr = w4 + (size_t)c * 16;
    v2f a0 = (v2f){0.f, 0.f}, a1 = (v2f){0.f, 0.f};
    v2f a2 = (v2f){0.f, 0.f}, a3 = (v2f){0.f, 0.f};
    v2f b0 = (v2f){0.f, 0.f}, b1 = (v2f){0.f, 0.f};
    v2f b2 = (v2f){0.f, 0.f}, b3 = (v2f){0.f, 0.f};
#pragma unroll
    for (int i = 0; i < 16; i += 2) {
      float4 t0 = wr[i];
      float4 t1 = wr[i + 1];
      a0 += (v2f){t0.x, t0.y} * xa[2 * i + 0];   // v_pk_fma_f32
      a1 += (v2f){t0.z, t0.w} * xa[2 * i + 1];
      a2 += (v2f){t1.x, t1.y} * xa[2 * i + 2];
      a3 += (v2f){t1.z, t1.w} * xa[2 * i + 3];
      b0 += (v2f){t0.x, t0.y} * xb[2 * i + 0];
      b1 += (v2f){t0.z, t0.w} * xb[2 * i + 1];
      b2 += (v2f){t1.x, t1.y} * xb[2 * i + 2];
      b3 += (v2f){t1.z, t1.w} * xb[2 * i + 3];
    }
    {
      v2f s01 = a0 + a1;
      v2f s23 = a2 + a3;
      v2f s = s01 + s23;
      float dot = s.x + s.y;
      float d = fmaf(-2.0f, dot, sxa + se[c]);
      if (d < bda) { bda = d; bca = c; }
    }
    {
      v2f s01 = b0 + b1;
      v2f s23 = b2 + b3;
      v2f s = s01 + s23;
      float dot = s.x + s.y;
      float d = fmaf(-2.0f, dot, sxb + se[c]);
      if (d < bdb) { bdb = d; bcb = c; }
    }
  }

  atomicMin(&keys[r0], ((unsigned long long)__float_as_uint(bda) << 32) |
                           (unsigned long long)(unsigned)bca);
  atomicMin(&keys[r1], ((unsigned long long)__float_as_uint(bdb) << 32) |
                           (unsigned long long)(unsigned)bcb);
}

// Phase 3 (grid 1024x256, 32 rows/block — R1/R6 verbatim): decode key ->
// index, indices (as float), STE output x + fl(w - x), fp64 partial ->
// part[b] plain store.
__global__ __launch_bounds__(256) void vq_out(const float* __restrict__ x,
                                              const float* __restrict__ w,
                                              const unsigned long long* __restrict__ keys,
                                              float* __restrict__ outq,
                                              float* __restrict__ outidx,
                                              double* __restrict__ part) {
  __shared__ int sidx[32];
  __shared__ double sp[4];
  const int b = blockIdx.x, t = threadIdx.x;

  if (t < 32) {
    const int row = b * 32 + t;
    unsigned long long k = keys[row];
    const int idx = (int)(unsigned int)(k & 0xFFFFFFFFull);
    outidx[row] = (float)idx;
    sidx[t] = idx;
  }
  __syncthreads();

  double acc = 0.0;
  const float4* x4 = (const float4*)x;
  float4* o4 = (float4*)outq;
#pragma unroll
  for (int i = 0; i < 2; ++i) {
    const int e = i * 256 + t;          // 0..511 float4s of this block's rows
    const int rl = e >> 4;              // local row (0..31)
    const int d4 = e & 15;              // float4 within the row
    const size_t gofs = ((size_t)b * 32 + rl) * 16 + d4;
    float4 xvv = x4[gofs];
    const float4* wr = (const float4*)(w + (size_t)sidx[rl] * DIM);
    float4 wv = wr[d4];
    float tx = wv.x - xvv.x, ty = wv.y - xvv.y;
    float tz = wv.z - xvv.z, tw = wv.w - xvv.w;
    float4 q;
    q.x = xvv.x + tx; q.y = xvv.y + ty;   // ref STE: x + fl(w - x)
    q.z = xvv.z + tz; q.w = xvv.w + tw;
    o4[gofs] = q;
    acc += (double)tx * tx + (double)ty * ty + (double)tz * tz + (double)tw * tw;
  }

#pragma unroll
  for (int s = 32; s > 0; s >>= 1) acc += __shfl_down(acc, s, 64);
  if ((t & 63) == 0) sp[t >> 6] = acc;
  __syncthreads();
  if (t == 0) part[b] = (sp[0] + sp[1]) + (sp[2] + sp[3]);
}

// Phase 4 (R1/R6 verbatim): reduce 1024 f64 partials, loss = 0.5 * mean.
__global__ __launch_bounds__(256) void vq_fin(const double* __restrict__ part,
                                              float* __restrict__ outloss) {
  __shared__ double sp[4];
  const int t = threadIdx.x;
  double a = (part[t] + part[t + 256]) + (part[t + 512] + part[t + 768]);
#pragma unroll
  for (int s = 32; s > 0; s >>= 1) a += __shfl_down(a, s, 64);
  if ((t & 63) == 0) sp[t >> 6] = a;
  __syncthreads();
  if (t == 0) {
    double total = (sp[0] + sp[1]) + (sp[2] + sp[3]);
    *outloss = 0.5f * (float)(total / (double)NELEM);
  }
}

extern "C" void kernel_launch(void* const* d_in, const int* in_sizes, int n_in,
                              void* d_out, int out_size, void* d_ws, size_t ws_size,
                              hipStream_t stream) {
  const float* x = (const float*)d_in[0];   // inputs (32,64,32,32) fp32
  const float* w = (const float*)d_in[1];   // weight (1024,64) fp32

  float* outq    = (float*)d_out;           // [0, 2097152)
  float* outidx  = outq + NELEM;            // [2097152, +32768)
  float* outloss = outidx + NROWS;          // [2129920]

  char* wsb = (char*)d_ws;
  float* se    = (float*)(wsb + 256);                               // 4 KB
  double* part = (double*)(wsb + 8192);                             // 8 KB
  unsigned long long* keys = (unsigned long long*)(wsb + 147456);   // 256 KB

  hipLaunchKernelGGL(vq_prep, dim3(128),  dim3(256), 0, stream, w, se, keys);
  hipLaunchKernelGGL(vq_dist, dim3(2048), dim3(256), 0, stream, x, w, se, keys);
  hipLaunchKernelGGL(vq_out,  dim3(1024), dim3(256), 0, stream, x, w, keys, outq, outidx, part);
  hipLaunchKernelGGL(vq_fin,  dim3(1),    dim3(256), 0, stream, part, outloss);
}